// Round 5
// baseline (516.420 us; speedup 1.0000x reference)
//
#include <hip/hip_runtime.h>

typedef unsigned short u16;
typedef short bf16x8 __attribute__((ext_vector_type(8)));
typedef float f32x4 __attribute__((ext_vector_type(4)));

#define MFMA16(a,b,c) __builtin_amdgcn_mfma_f32_16x16x32_bf16((a),(b),(c),0,0,0)
#define NEGHUGE (-1.0e30f)

__device__ __forceinline__ u16 f2b(float f){
  union { float f; unsigned int i; } v; v.f = f;
  unsigned int r = v.i + 0x7FFFu + ((v.i>>16)&1u);
  return (u16)(r>>16);
}

union BfPack { u16 h[8]; bf16x8 v; uint4 u; };

__device__ __forceinline__ uint4 pack8u(const float* __restrict__ p){
  float4 a = *(const float4*)p;
  float4 b = *(const float4*)(p + 4);
  BfPack r;
  r.h[0]=f2b(a.x); r.h[1]=f2b(a.y); r.h[2]=f2b(a.z); r.h[3]=f2b(a.w);
  r.h[4]=f2b(b.x); r.h[5]=f2b(b.y); r.h[6]=f2b(b.z); r.h[7]=f2b(b.w);
  return r.u;
}

// ---------------- kernel 1: f32 -> bf16 for w_qkv, w_out (weights only) ------
__global__ __launch_bounds__(256) void k_convert_w(
    const float* __restrict__ wqkv, const float* __restrict__ wout,
    u16* __restrict__ wqkvb, u16* __restrict__ woutb)
{
  int idx = (int)blockIdx.x * 256 + threadIdx.x;      // float4 groups
  const float* src; u16* dst; int off;
  if (idx < 110592) { src = wqkv; dst = wqkvb; off = idx; }
  else              { src = wout; dst = woutb; off = idx - 110592;
                      if (off >= 36864) return; }
  float4 f = ((const float4*)src)[off];
  union { u16 h[4]; uint2 u; } p;
  p.h[0]=f2b(f.x); p.h[1]=f2b(f.y); p.h[2]=f2b(f.z); p.h[3]=f2b(f.w);
  ((uint2*)dst)[off] = p.u;
}

// ---------------- kernel 2: QKV GEMM (f32 x staged+converted to LDS) ---------
// m indexes SHIFTED space; source row = (coord+3) % 56.  qkvs written linear.
__global__ __launch_bounds__(256) void k_qkv(
    const float* __restrict__ x, const u16* __restrict__ wqkvb,
    u16* __restrict__ qkvs)
{
  __shared__ u16 At[64][392];   // 64 x 384 bf16 A-tile, +8 pad (2-way banks: free)
  const int tid = threadIdx.x;
  const int wv = tid >> 6, lane = tid & 63, quad = lane >> 4, l16 = lane & 15;
  const int m0 = (int)blockIdx.x * 64;                // 784 blocks

  // stage + convert: 64 rows x 48 chunks of 8 floats
  for (int i = tid; i < 64*48; i += 256) {
    int row = i / 48, g = i % 48;
    int m = m0 + row;
    int b = m / 3136, rm = m - b*3136, hs = rm / 56, ws_ = rm - hs*56;
    int h = hs + 3; if (h >= 56) h -= 56;             // shifted -> source coord
    int w = ws_ + 3; if (w >= 56) w -= 56;
    const float* src = x + ((size_t)((b*56 + h)*56 + w)*384 + g*8);
    *(uint4*)(&At[row][g*8]) = pack8u(src);
  }
  __syncthreads();

  for (int nt = wv; nt < 18; nt += 4) {               // waves cover 18 n-tiles
    const int n0 = nt * 64;
    f32x4 acc[4][4];
    #pragma unroll
    for (int mi = 0; mi < 4; ++mi)
      #pragma unroll
      for (int j = 0; j < 4; ++j) acc[mi][j] = f32x4{0.f,0.f,0.f,0.f};

    for (int k = 0; k < 12; ++k) {
      bf16x8 a[4], bb[4];
      #pragma unroll
      for (int mi = 0; mi < 4; ++mi)
        a[mi] = *(const bf16x8*)(&At[mi*16 + l16][k*32 + quad*8]);
      #pragma unroll
      for (int j = 0; j < 4; ++j)
        bb[j] = *(const bf16x8*)(&wqkvb[(size_t)(n0 + j*16 + l16)*384 + k*32 + quad*8]);
      #pragma unroll
      for (int mi = 0; mi < 4; ++mi)
        #pragma unroll
        for (int j = 0; j < 4; ++j)
          acc[mi][j] = MFMA16(a[mi], bb[j], acc[mi][j]);
    }

    #pragma unroll
    for (int mi = 0; mi < 4; ++mi)
      #pragma unroll
      for (int r = 0; r < 4; ++r) {
        const int m = m0 + mi*16 + quad*4 + r;
        u16* dst = qkvs + (size_t)m*1152 + n0;
        #pragma unroll
        for (int j = 0; j < 4; ++j)
          dst[j*16 + l16] = f2b(acc[mi][j][r]);
      }
  }
}

// ---------------- kernel 3: windowed attention, 1 wave per (window, head) -----
struct __align__(16) SmemT {
  u16 Vt[4][32][72];    // per-wave V^T [d][pos]; pos 49..63 zeroed
  u16 P[4][64][72];     // per-wave softmax probs
  float relb[4][169];   // per-wave rel-pos table column
};

__global__ __launch_bounds__(256) void k_attn(
    const u16* __restrict__ qkvs, const float* __restrict__ relt,
    u16* __restrict__ attnb)
{
  __shared__ SmemT S;
  const int tid = threadIdx.x;
  const int wv = tid >> 6, lane = tid & 63, quad = lane >> 4, l16 = lane & 15;
  const int blk = (int)blockIdx.x;                 // 3072 blocks
  const int b = blk / 192, r0 = blk % 192, win = r0 / 3, hg = r0 % 3;
  const int hb = win >> 3, wb = win & 7, head = hg*4 + wv;

  for (int i = lane; i < 169; i += 64) S.relb[wv][i] = relt[i*12 + head];

  // stage V^T: lane = pos
  {
    const int pos = lane;
    u16 vh[32];
    if (pos < 49) {
      int py = pos / 7, px = pos - py*7;
      const uint4* src = (const uint4*)(qkvs +
          (size_t)((b*56 + hb*7+py)*56 + wb*7+px)*1152 + 768 + head*32);
      #pragma unroll
      for (int t = 0; t < 4; ++t) *(uint4*)(&vh[t*8]) = src[t];
    } else {
      #pragma unroll
      for (int t = 0; t < 4; ++t) *(uint4*)(&vh[t*8]) = uint4{0,0,0,0};
    }
    #pragma unroll
    for (int d = 0; d < 32; ++d) S.Vt[wv][d][pos] = vh[d];
  }

  // Q / K fragments straight from global (A: m=pos, B: n=pos; k = quad*8..)
  bf16x8 aq[4], bk[4];
  #pragma unroll
  for (int mt = 0; mt < 4; ++mt) {
    int pos = mt*16 + l16; if (pos > 48) pos = 48;   // clamp; masked later
    int py = pos / 7, px = pos - py*7;
    const u16* src = qkvs + (size_t)((b*56 + hb*7+py)*56 + wb*7+px)*1152
                   + head*32 + quad*8;
    aq[mt] = *(const bf16x8*)src;          // Q part
    bk[mt] = *(const bf16x8*)(src + 384);  // K part
  }
  __syncthreads();

  // QK^T
  f32x4 sc[4][4];
  #pragma unroll
  for (int mt = 0; mt < 4; ++mt)
    #pragma unroll
    for (int n = 0; n < 4; ++n) {
      f32x4 z = {0.f,0.f,0.f,0.f};
      sc[mt][n] = MFMA16(aq[mt], bk[n], z);
    }

  // bias + mask + softmax
  #pragma unroll
  for (int mt = 0; mt < 4; ++mt)
    #pragma unroll
    for (int r = 0; r < 4; ++r) {
      const int q = mt*16 + quad*4 + r;
      const int qy = q / 7, qx = q - qy*7;
      #pragma unroll
      for (int n = 0; n < 4; ++n) {
        const int key = n*16 + l16;
        float s = sc[mt][n][r] * 0.17677669529663687f;   // 1/sqrt(32)
        if (key < 49 && q < 49) {
          const int ky = key / 7, kx = key - ky*7;
          s += S.relb[wv][(ky - qy + 6)*13 + (kx - qx + 6)];
          if (hb == 7 && ((qy >= 4) != (ky >= 4))) s = NEGHUGE;  // UL mask
        } else {
          s = NEGHUGE;
        }
        sc[mt][n][r] = s;
      }
      float mx = fmaxf(fmaxf(sc[mt][0][r], sc[mt][1][r]),
                       fmaxf(sc[mt][2][r], sc[mt][3][r]));
      mx = fmaxf(mx, __shfl_xor(mx, 1));
      mx = fmaxf(mx, __shfl_xor(mx, 2));
      mx = fmaxf(mx, __shfl_xor(mx, 4));
      mx = fmaxf(mx, __shfl_xor(mx, 8));
      float sum = 0.f;
      #pragma unroll
      for (int n = 0; n < 4; ++n) {
        float p = exp2f((sc[mt][n][r] - mx) * 1.4426950408889634f);
        sc[mt][n][r] = p; sum += p;
      }
      sum += __shfl_xor(sum, 1);
      sum += __shfl_xor(sum, 2);
      sum += __shfl_xor(sum, 4);
      sum += __shfl_xor(sum, 8);
      const float rinv = 1.0f / sum;
      #pragma unroll
      for (int n = 0; n < 4; ++n)
        S.P[wv][q][n*16 + l16] = f2b(sc[mt][n][r] * rinv);
    }
  __syncthreads();

  // PV
  #pragma unroll
  for (int mt = 0; mt < 4; ++mt) {
    bf16x8 ap0 = *(const bf16x8*)(&S.P[wv][mt*16 + l16][quad*8]);
    bf16x8 ap1 = *(const bf16x8*)(&S.P[wv][mt*16 + l16][32 + quad*8]);
    #pragma unroll
    for (int n2 = 0; n2 < 2; ++n2) {
      bf16x8 bv0 = *(const bf16x8*)(&S.Vt[wv][n2*16 + l16][quad*8]);
      bf16x8 bv1 = *(const bf16x8*)(&S.Vt[wv][n2*16 + l16][32 + quad*8]);
      f32x4 o = {0.f,0.f,0.f,0.f};
      o = MFMA16(ap0, bv0, o);
      o = MFMA16(ap1, bv1, o);
      #pragma unroll
      for (int r = 0; r < 4; ++r) {
        int q = mt*16 + quad*4 + r;
        if (q < 49) {
          int py = q / 7, px = q - py*7;
          attnb[(size_t)((b*56 + hb*7+py)*56 + wb*7+px)*384
                + head*32 + n2*16 + l16] = f2b(o[r]);
        }
      }
    }
  }
}

// ---------------- kernel 4: out = attn @ w_out^T + b_out, inverse roll(+3) ---
__global__ __launch_bounds__(384) void k_proj(
    const u16* __restrict__ attnb, const u16* __restrict__ woutb,
    const float* __restrict__ bout, float* __restrict__ out)
{
  __shared__ u16 At[64][392];   // attn m-tile, staged once, read by 6 waves
  const int tid = threadIdx.x;
  const int wv = tid >> 6, lane = tid & 63, quad = lane >> 4, l16 = lane & 15;
  const int m0 = (int)blockIdx.x * 64;               // 784 blocks
  const int n0 = wv * 64;                            // 6 waves cover N=384

  for (int i = tid; i < 64*48; i += 384) {
    int row = i / 48, g = i % 48;
    *(uint4*)(&At[row][g*8]) =
        *(const uint4*)(&attnb[(size_t)(m0 + row)*384 + g*8]);
  }
  __syncthreads();

  f32x4 acc[4][4];
  #pragma unroll
  for (int mi = 0; mi < 4; ++mi)
    #pragma unroll
    for (int j = 0; j < 4; ++j) acc[mi][j] = f32x4{0.f,0.f,0.f,0.f};

  for (int k = 0; k < 12; ++k) {
    bf16x8 a[4], bb[4];
    #pragma unroll
    for (int mi = 0; mi < 4; ++mi)
      a[mi] = *(const bf16x8*)(&At[mi*16 + l16][k*32 + quad*8]);
    #pragma unroll
    for (int j = 0; j < 4; ++j)
      bb[j] = *(const bf16x8*)(&woutb[(size_t)(n0 + j*16 + l16)*384 + k*32 + quad*8]);
    #pragma unroll
    for (int mi = 0; mi < 4; ++mi)
      #pragma unroll
      for (int j = 0; j < 4; ++j)
        acc[mi][j] = MFMA16(a[mi], bb[j], acc[mi][j]);
  }

  #pragma unroll
  for (int j = 0; j < 4; ++j) {
    const int col = n0 + j*16 + l16;
    const float bias = bout[col];
    #pragma unroll
    for (int mi = 0; mi < 4; ++mi)
      #pragma unroll
      for (int r = 0; r < 4; ++r) {
        int m = m0 + mi*16 + quad*4 + r;
        int w = m % 56; int t = m / 56; int h = t % 56; int bb2 = t / 56;
        int h_ = h + 3; if (h_ >= 56) h_ -= 56;      // inverse roll (+3)
        int w_ = w + 3; if (w_ >= 56) w_ -= 56;
        out[((size_t)(bb2*56 + h_)*56 + w_)*384 + col] = acc[mi][j][r] + bias;
      }
  }
}

extern "C" void kernel_launch(void* const* d_in, const int* in_sizes, int n_in,
                              void* d_out, int out_size, void* d_ws, size_t ws_size,
                              hipStream_t stream) {
  const float* x    = (const float*)d_in[0];
  const float* wqkv = (const float*)d_in[1];
  const float* wout = (const float*)d_in[2];
  const float* bout = (const float*)d_in[3];
  const float* relt = (const float*)d_in[4];

  char* ws = (char*)d_ws;
  u16* qkvs  = (u16*)(ws);                        // 115,605,504 B
  u16* wqkvb = (u16*)(ws + 115605504);            //     884,736 B
  u16* woutb = (u16*)(ws + 116490240);            //     294,912 B
  u16* attnb = (u16*)(ws + 116785152);            //  38,535,168 B
  float* outp = (float*)d_out;

  k_convert_w<<<576, 256, 0, stream>>>(wqkv, wout, wqkvb, woutb);
  k_qkv<<<784, 256, 0, stream>>>(x, wqkvb, qkvs);
  k_attn<<<3072, 256, 0, stream>>>(qkvs, relt, attnb);
  k_proj<<<784, 384, 0, stream>>>(attnb, woutb, bout, outp);
}

// Round 6
// 418.438 us; speedup vs baseline: 1.2342x; 1.2342x over previous
//
#include <hip/hip_runtime.h>

typedef unsigned short u16;
typedef short bf16x8 __attribute__((ext_vector_type(8)));
typedef float f32x4 __attribute__((ext_vector_type(4)));

#define MFMA16(a,b,c) __builtin_amdgcn_mfma_f32_16x16x32_bf16((a),(b),(c),0,0,0)
#define NEGHUGE (-1.0e30f)

__device__ __forceinline__ u16 f2b(float f){
  union { float f; unsigned int i; } v; v.f = f;
  unsigned int r = v.i + 0x7FFFu + ((v.i>>16)&1u);
  return (u16)(r>>16);
}

union BfPack { u16 h[8]; bf16x8 v; uint4 u; };

__device__ __forceinline__ uint4 pack8u(const float* __restrict__ p){
  float4 a = *(const float4*)p;
  float4 b = *(const float4*)(p + 4);
  BfPack r;
  r.h[0]=f2b(a.x); r.h[1]=f2b(a.y); r.h[2]=f2b(a.z); r.h[3]=f2b(a.w);
  r.h[4]=f2b(b.x); r.h[5]=f2b(b.y); r.h[6]=f2b(b.z); r.h[7]=f2b(b.w);
  return r.u;
}

// ---------------- kernel 1: f32 -> bf16 for w_qkv, w_out (weights only) ------
__global__ __launch_bounds__(256) void k_convert_w(
    const float* __restrict__ wqkv, const float* __restrict__ wout,
    u16* __restrict__ wqkvb, u16* __restrict__ woutb)
{
  int idx = (int)blockIdx.x * 256 + threadIdx.x;      // float4 groups
  const float* src; u16* dst; int off;
  if (idx < 110592) { src = wqkv; dst = wqkvb; off = idx; }
  else              { src = wout; dst = woutb; off = idx - 110592;
                      if (off >= 36864) return; }
  float4 f = ((const float4*)src)[off];
  union { u16 h[4]; uint2 u; } p;
  p.h[0]=f2b(f.x); p.h[1]=f2b(f.y); p.h[2]=f2b(f.z); p.h[3]=f2b(f.w);
  ((uint2*)dst)[off] = p.u;
}

// ---------------- kernel 2: QKV GEMM ------------------------------------------
// block = 6 waves; ONE n-tile per wave (no serial tile loop -> low VGPR, high
// occupancy). A-tile (64x384 bf16, converted from f32 x with shift applied)
// staged once per block; B fragments from L2-hot bf16 weights.
// m indexes SHIFTED space; source row = (coord+3) % 56. qkvs written linear.
__global__ __launch_bounds__(384, 4) void k_qkv(
    const float* __restrict__ x, const u16* __restrict__ wqkvb,
    u16* __restrict__ qkvs)
{
  __shared__ u16 At[64][392];   // stride 784B = 49x16B: aligned, <=2-way banks
  const int tid = threadIdx.x;
  const int wv = tid >> 6, lane = tid & 63, quad = lane >> 4, l16 = lane & 15;
  const int m0 = ((int)blockIdx.x / 3) * 64;          // 784 m-tiles x 3 groups
  const int n0 = (((int)blockIdx.x % 3) * 6 + wv) * 64;

  // stage + convert: 64 rows x 48 chunks of 8 floats (8 iters/thread)
  for (int i = tid; i < 64*48; i += 384) {
    int row = i / 48, g = i % 48;
    int m = m0 + row;
    int b = m / 3136, rm = m - b*3136, hs = rm / 56, ws_ = rm - hs*56;
    int h = hs + 3; if (h >= 56) h -= 56;             // shifted -> source coord
    int w = ws_ + 3; if (w >= 56) w -= 56;
    const float* src = x + ((size_t)((b*56 + h)*56 + w)*384 + g*8);
    *(uint4*)(&At[row][g*8]) = pack8u(src);
  }
  __syncthreads();

  f32x4 acc[4][4];
  #pragma unroll
  for (int mi = 0; mi < 4; ++mi)
    #pragma unroll
    for (int j = 0; j < 4; ++j) acc[mi][j] = f32x4{0.f,0.f,0.f,0.f};

  for (int k = 0; k < 12; ++k) {
    bf16x8 a[4], bb[4];
    #pragma unroll
    for (int mi = 0; mi < 4; ++mi)
      a[mi] = *(const bf16x8*)(&At[mi*16 + l16][k*32 + quad*8]);
    #pragma unroll
    for (int j = 0; j < 4; ++j)
      bb[j] = *(const bf16x8*)(&wqkvb[(size_t)(n0 + j*16 + l16)*384 + k*32 + quad*8]);
    #pragma unroll
    for (int mi = 0; mi < 4; ++mi)
      #pragma unroll
      for (int j = 0; j < 4; ++j)
        acc[mi][j] = MFMA16(a[mi], bb[j], acc[mi][j]);
  }

  #pragma unroll
  for (int mi = 0; mi < 4; ++mi)
    #pragma unroll
    for (int r = 0; r < 4; ++r) {
      const int m = m0 + mi*16 + quad*4 + r;
      u16* dst = qkvs + (size_t)m*1152 + n0;
      #pragma unroll
      for (int j = 0; j < 4; ++j)
        dst[j*16 + l16] = f2b(acc[mi][j][r]);
    }
}

// ---------------- kernel 3: windowed attention, 1 wave per (window, head) -----
struct __align__(16) SmemT {
  u16 Vt[4][32][72];    // per-wave V^T [d][pos]; pos 49..63 zeroed
  u16 P[4][64][72];     // per-wave softmax probs
  float relb[4][169];   // per-wave rel-pos table column
};

__global__ __launch_bounds__(256) void k_attn(
    const u16* __restrict__ qkvs, const float* __restrict__ relt,
    u16* __restrict__ attnb)
{
  __shared__ SmemT S;
  const int tid = threadIdx.x;
  const int wv = tid >> 6, lane = tid & 63, quad = lane >> 4, l16 = lane & 15;
  const int blk = (int)blockIdx.x;                 // 3072 blocks
  const int b = blk / 192, r0 = blk % 192, win = r0 / 3, hg = r0 % 3;
  const int hb = win >> 3, wb = win & 7, head = hg*4 + wv;

  for (int i = lane; i < 169; i += 64) S.relb[wv][i] = relt[i*12 + head];

  // stage V^T: lane = pos
  {
    const int pos = lane;
    u16 vh[32];
    if (pos < 49) {
      int py = pos / 7, px = pos - py*7;
      const uint4* src = (const uint4*)(qkvs +
          (size_t)((b*56 + hb*7+py)*56 + wb*7+px)*1152 + 768 + head*32);
      #pragma unroll
      for (int t = 0; t < 4; ++t) *(uint4*)(&vh[t*8]) = src[t];
    } else {
      #pragma unroll
      for (int t = 0; t < 4; ++t) *(uint4*)(&vh[t*8]) = uint4{0,0,0,0};
    }
    #pragma unroll
    for (int d = 0; d < 32; ++d) S.Vt[wv][d][pos] = vh[d];
  }

  // Q / K fragments straight from global (A: m=pos, B: n=pos; k = quad*8..)
  bf16x8 aq[4], bk[4];
  #pragma unroll
  for (int mt = 0; mt < 4; ++mt) {
    int pos = mt*16 + l16; if (pos > 48) pos = 48;   // clamp; masked later
    int py = pos / 7, px = pos - py*7;
    const u16* src = qkvs + (size_t)((b*56 + hb*7+py)*56 + wb*7+px)*1152
                   + head*32 + quad*8;
    aq[mt] = *(const bf16x8*)src;          // Q part
    bk[mt] = *(const bf16x8*)(src + 384);  // K part
  }
  __syncthreads();

  // QK^T
  f32x4 sc[4][4];
  #pragma unroll
  for (int mt = 0; mt < 4; ++mt)
    #pragma unroll
    for (int n = 0; n < 4; ++n) {
      f32x4 z = {0.f,0.f,0.f,0.f};
      sc[mt][n] = MFMA16(aq[mt], bk[n], z);
    }

  // bias + mask + softmax
  #pragma unroll
  for (int mt = 0; mt < 4; ++mt)
    #pragma unroll
    for (int r = 0; r < 4; ++r) {
      const int q = mt*16 + quad*4 + r;
      const int qy = q / 7, qx = q - qy*7;
      #pragma unroll
      for (int n = 0; n < 4; ++n) {
        const int key = n*16 + l16;
        float s = sc[mt][n][r] * 0.17677669529663687f;   // 1/sqrt(32)
        if (key < 49 && q < 49) {
          const int ky = key / 7, kx = key - ky*7;
          s += S.relb[wv][(ky - qy + 6)*13 + (kx - qx + 6)];
          if (hb == 7 && ((qy >= 4) != (ky >= 4))) s = NEGHUGE;  // UL mask
        } else {
          s = NEGHUGE;
        }
        sc[mt][n][r] = s;
      }
      float mx = fmaxf(fmaxf(sc[mt][0][r], sc[mt][1][r]),
                       fmaxf(sc[mt][2][r], sc[mt][3][r]));
      mx = fmaxf(mx, __shfl_xor(mx, 1));
      mx = fmaxf(mx, __shfl_xor(mx, 2));
      mx = fmaxf(mx, __shfl_xor(mx, 4));
      mx = fmaxf(mx, __shfl_xor(mx, 8));
      float sum = 0.f;
      #pragma unroll
      for (int n = 0; n < 4; ++n) {
        float p = exp2f((sc[mt][n][r] - mx) * 1.4426950408889634f);
        sc[mt][n][r] = p; sum += p;
      }
      sum += __shfl_xor(sum, 1);
      sum += __shfl_xor(sum, 2);
      sum += __shfl_xor(sum, 4);
      sum += __shfl_xor(sum, 8);
      const float rinv = 1.0f / sum;
      #pragma unroll
      for (int n = 0; n < 4; ++n)
        S.P[wv][q][n*16 + l16] = f2b(sc[mt][n][r] * rinv);
    }
  __syncthreads();

  // PV
  #pragma unroll
  for (int mt = 0; mt < 4; ++mt) {
    bf16x8 ap0 = *(const bf16x8*)(&S.P[wv][mt*16 + l16][quad*8]);
    bf16x8 ap1 = *(const bf16x8*)(&S.P[wv][mt*16 + l16][32 + quad*8]);
    #pragma unroll
    for (int n2 = 0; n2 < 2; ++n2) {
      bf16x8 bv0 = *(const bf16x8*)(&S.Vt[wv][n2*16 + l16][quad*8]);
      bf16x8 bv1 = *(const bf16x8*)(&S.Vt[wv][n2*16 + l16][32 + quad*8]);
      f32x4 o = {0.f,0.f,0.f,0.f};
      o = MFMA16(ap0, bv0, o);
      o = MFMA16(ap1, bv1, o);
      #pragma unroll
      for (int r = 0; r < 4; ++r) {
        int q = mt*16 + quad*4 + r;
        if (q < 49) {
          int py = q / 7, px = q - py*7;
          attnb[(size_t)((b*56 + hb*7+py)*56 + wb*7+px)*384
                + head*32 + n2*16 + l16] = f2b(o[r]);
        }
      }
    }
  }
}

// ---------------- kernel 4: out = attn @ w_out^T + b_out, inverse roll(+3) ---
__global__ __launch_bounds__(384, 4) void k_proj(
    const u16* __restrict__ attnb, const u16* __restrict__ woutb,
    const float* __restrict__ bout, float* __restrict__ out)
{
  __shared__ u16 At[64][392];   // attn m-tile, staged once, read by 6 waves
  const int tid = threadIdx.x;
  const int wv = tid >> 6, lane = tid & 63, quad = lane >> 4, l16 = lane & 15;
  const int m0 = (int)blockIdx.x * 64;               // 784 blocks
  const int n0 = wv * 64;                            // 6 waves cover N=384

  for (int i = tid; i < 64*48; i += 384) {
    int row = i / 48, g = i % 48;
    *(uint4*)(&At[row][g*8]) =
        *(const uint4*)(&attnb[(size_t)(m0 + row)*384 + g*8]);
  }
  __syncthreads();

  f32x4 acc[4][4];
  #pragma unroll
  for (int mi = 0; mi < 4; ++mi)
    #pragma unroll
    for (int j = 0; j < 4; ++j) acc[mi][j] = f32x4{0.f,0.f,0.f,0.f};

  for (int k = 0; k < 12; ++k) {
    bf16x8 a[4], bb[4];
    #pragma unroll
    for (int mi = 0; mi < 4; ++mi)
      a[mi] = *(const bf16x8*)(&At[mi*16 + l16][k*32 + quad*8]);
    #pragma unroll
    for (int j = 0; j < 4; ++j)
      bb[j] = *(const bf16x8*)(&woutb[(size_t)(n0 + j*16 + l16)*384 + k*32 + quad*8]);
    #pragma unroll
    for (int mi = 0; mi < 4; ++mi)
      #pragma unroll
      for (int j = 0; j < 4; ++j)
        acc[mi][j] = MFMA16(a[mi], bb[j], acc[mi][j]);
  }

  #pragma unroll
  for (int j = 0; j < 4; ++j) {
    const int col = n0 + j*16 + l16;
    const float bias = bout[col];
    #pragma unroll
    for (int mi = 0; mi < 4; ++mi)
      #pragma unroll
      for (int r = 0; r < 4; ++r) {
        int m = m0 + mi*16 + quad*4 + r;
        int w = m % 56; int t = m / 56; int h = t % 56; int bb2 = t / 56;
        int h_ = h + 3; if (h_ >= 56) h_ -= 56;      // inverse roll (+3)
        int w_ = w + 3; if (w_ >= 56) w_ -= 56;
        out[((size_t)(bb2*56 + h_)*56 + w_)*384 + col] = acc[mi][j][r] + bias;
      }
  }
}

extern "C" void kernel_launch(void* const* d_in, const int* in_sizes, int n_in,
                              void* d_out, int out_size, void* d_ws, size_t ws_size,
                              hipStream_t stream) {
  const float* x    = (const float*)d_in[0];
  const float* wqkv = (const float*)d_in[1];
  const float* wout = (const float*)d_in[2];
  const float* bout = (const float*)d_in[3];
  const float* relt = (const float*)d_in[4];

  char* ws = (char*)d_ws;
  u16* qkvs  = (u16*)(ws);                        // 115,605,504 B
  u16* wqkvb = (u16*)(ws + 115605504);            //     884,736 B
  u16* woutb = (u16*)(ws + 116490240);            //     294,912 B
  u16* attnb = (u16*)(ws + 116785152);            //  38,535,168 B
  float* outp = (float*)d_out;

  k_convert_w<<<576, 256, 0, stream>>>(wqkv, wout, wqkvb, woutb);
  k_qkv<<<2352, 384, 0, stream>>>(x, wqkvb, qkvs);
  k_attn<<<3072, 256, 0, stream>>>(qkvs, relt, attnb);
  k_proj<<<784, 384, 0, stream>>>(attnb, woutb, bout, outp);
}

// Round 7
// 390.257 us; speedup vs baseline: 1.3233x; 1.0722x over previous
//
#include <hip/hip_runtime.h>

typedef unsigned short u16;
typedef short bf16x8 __attribute__((ext_vector_type(8)));
typedef float f32x4 __attribute__((ext_vector_type(4)));

#define MFMA16(a,b,c) __builtin_amdgcn_mfma_f32_16x16x32_bf16((a),(b),(c),0,0,0)
#define NEGHUGE (-1.0e30f)

__device__ __forceinline__ u16 f2b(float f){
  union { float f; unsigned int i; } v; v.f = f;
  unsigned int r = v.i + 0x7FFFu + ((v.i>>16)&1u);
  return (u16)(r>>16);
}

union BfPack { u16 h[8]; bf16x8 v; uint4 u; };

__device__ __forceinline__ uint4 pack8u(const float* __restrict__ p){
  float4 a = *(const float4*)p;
  float4 b = *(const float4*)(p + 4);
  BfPack r;
  r.h[0]=f2b(a.x); r.h[1]=f2b(a.y); r.h[2]=f2b(a.z); r.h[3]=f2b(a.w);
  r.h[4]=f2b(b.x); r.h[5]=f2b(b.y); r.h[6]=f2b(b.z); r.h[7]=f2b(b.w);
  return r.u;
}

// ---------------- kernel 1: f32 -> bf16 for w_qkv, w_out (weights only) ------
__global__ __launch_bounds__(256) void k_convert_w(
    const float* __restrict__ wqkv, const float* __restrict__ wout,
    u16* __restrict__ wqkvb, u16* __restrict__ woutb)
{
  int idx = (int)blockIdx.x * 256 + threadIdx.x;      // float4 groups
  const float* src; u16* dst; int off;
  if (idx < 110592) { src = wqkv; dst = wqkvb; off = idx; }
  else              { src = wout; dst = woutb; off = idx - 110592;
                      if (off >= 36864) return; }
  float4 f = ((const float4*)src)[off];
  union { u16 h[4]; uint2 u; } p;
  p.h[0]=f2b(f.x); p.h[1]=f2b(f.y); p.h[2]=f2b(f.z); p.h[3]=f2b(f.w);
  ((uint2*)dst)[off] = p.u;
}

// ---------------- kernel 2: QKV GEMM ------------------------------------------
// block = 6 waves, one 64-col n-tile per wave; A-tile staged+converted to LDS;
// epilogue round-trips acc through the A-tile LDS so qkvs stores are
// cooperative uint4 (768 B contiguous per row) instead of 64 scalar shorts.
__global__ __launch_bounds__(384, 4) void k_qkv(
    const float* __restrict__ x, const u16* __restrict__ wqkvb,
    u16* __restrict__ qkvs)
{
  __shared__ u16 At[64][392];   // stride 784B: 16B-aligned rows
  const int tid = threadIdx.x;
  const int wv = tid >> 6, lane = tid & 63, quad = lane >> 4, l16 = lane & 15;
  const int m0 = ((int)blockIdx.x / 3) * 64;          // 784 m-tiles x 3 groups
  const int ng = (int)blockIdx.x % 3;
  const int n0 = (ng * 6 + wv) * 64;

  // stage + convert: 64 rows x 48 chunks of 8 floats (shift applied on load)
  for (int i = tid; i < 64*48; i += 384) {
    int row = i / 48, g = i % 48;
    int m = m0 + row;
    int b = m / 3136, rm = m - b*3136, hs = rm / 56, ws_ = rm - hs*56;
    int h = hs + 3; if (h >= 56) h -= 56;             // shifted -> source coord
    int w = ws_ + 3; if (w >= 56) w -= 56;
    const float* src = x + ((size_t)((b*56 + h)*56 + w)*384 + g*8);
    *(uint4*)(&At[row][g*8]) = pack8u(src);
  }
  __syncthreads();

  f32x4 acc[4][4];
  #pragma unroll
  for (int mi = 0; mi < 4; ++mi)
    #pragma unroll
    for (int j = 0; j < 4; ++j) acc[mi][j] = f32x4{0.f,0.f,0.f,0.f};

  for (int k = 0; k < 12; ++k) {
    bf16x8 a[4], bb[4];
    #pragma unroll
    for (int mi = 0; mi < 4; ++mi)
      a[mi] = *(const bf16x8*)(&At[mi*16 + l16][k*32 + quad*8]);
    #pragma unroll
    for (int j = 0; j < 4; ++j)
      bb[j] = *(const bf16x8*)(&wqkvb[(size_t)(n0 + j*16 + l16)*384 + k*32 + quad*8]);
    #pragma unroll
    for (int mi = 0; mi < 4; ++mi)
      #pragma unroll
      for (int j = 0; j < 4; ++j)
        acc[mi][j] = MFMA16(a[mi], bb[j], acc[mi][j]);
  }
  __syncthreads();   // A-tile reads done; reuse At as output staging

  #pragma unroll
  for (int mi = 0; mi < 4; ++mi)
    #pragma unroll
    for (int j = 0; j < 4; ++j)
      #pragma unroll
      for (int r = 0; r < 4; ++r)
        At[mi*16 + quad*4 + r][wv*64 + j*16 + l16] = f2b(acc[mi][j][r]);
  __syncthreads();

  // cooperative coalesced store: 64 rows x 768 B contiguous spans
  for (int i = tid; i < 64*48; i += 384) {
    int row = i / 48, g = i % 48;
    *(uint4*)(qkvs + (size_t)(m0 + row)*1152 + ng*384 + g*8) =
        *(const uint4*)(&At[row][g*8]);
  }
}

// ---------------- kernel 3: windowed attention, 1 wave per (window, head) -----
// Output written at ORIGINAL (rolled +3) coordinates so k_proj is fully linear.
struct __align__(16) SmemT {
  u16 Vt[4][32][72];    // per-wave V^T [d][pos]; pos 49..63 zeroed
  u16 P[4][64][72];     // per-wave softmax probs
  float relb[4][169];   // per-wave rel-pos table column
};

__global__ __launch_bounds__(256) void k_attn(
    const u16* __restrict__ qkvs, const float* __restrict__ relt,
    u16* __restrict__ attnb)
{
  __shared__ SmemT S;
  const int tid = threadIdx.x;
  const int wv = tid >> 6, lane = tid & 63, quad = lane >> 4, l16 = lane & 15;
  const int blk = (int)blockIdx.x;                 // 3072 blocks
  const int b = blk / 192, r0 = blk % 192, win = r0 / 3, hg = r0 % 3;
  const int hb = win >> 3, wb = win & 7, head = hg*4 + wv;

  for (int i = lane; i < 169; i += 64) S.relb[wv][i] = relt[i*12 + head];

  // stage V^T: lane = pos
  {
    const int pos = lane;
    u16 vh[32];
    if (pos < 49) {
      int py = pos / 7, px = pos - py*7;
      const uint4* src = (const uint4*)(qkvs +
          (size_t)((b*56 + hb*7+py)*56 + wb*7+px)*1152 + 768 + head*32);
      #pragma unroll
      for (int t = 0; t < 4; ++t) *(uint4*)(&vh[t*8]) = src[t];
    } else {
      #pragma unroll
      for (int t = 0; t < 4; ++t) *(uint4*)(&vh[t*8]) = uint4{0,0,0,0};
    }
    #pragma unroll
    for (int d = 0; d < 32; ++d) S.Vt[wv][d][pos] = vh[d];
  }

  // Q / K fragments straight from global (A: m=pos, B: n=pos; k = quad*8..)
  bf16x8 aq[4], bk[4];
  #pragma unroll
  for (int mt = 0; mt < 4; ++mt) {
    int pos = mt*16 + l16; if (pos > 48) pos = 48;   // clamp; masked later
    int py = pos / 7, px = pos - py*7;
    const u16* src = qkvs + (size_t)((b*56 + hb*7+py)*56 + wb*7+px)*1152
                   + head*32 + quad*8;
    aq[mt] = *(const bf16x8*)src;          // Q part
    bk[mt] = *(const bf16x8*)(src + 384);  // K part
  }
  __syncthreads();

  // QK^T
  f32x4 sc[4][4];
  #pragma unroll
  for (int mt = 0; mt < 4; ++mt)
    #pragma unroll
    for (int n = 0; n < 4; ++n) {
      f32x4 z = {0.f,0.f,0.f,0.f};
      sc[mt][n] = MFMA16(aq[mt], bk[n], z);
    }

  // bias + mask + softmax
  #pragma unroll
  for (int mt = 0; mt < 4; ++mt)
    #pragma unroll
    for (int r = 0; r < 4; ++r) {
      const int q = mt*16 + quad*4 + r;
      const int qy = q / 7, qx = q - qy*7;
      #pragma unroll
      for (int n = 0; n < 4; ++n) {
        const int key = n*16 + l16;
        float s = sc[mt][n][r] * 0.17677669529663687f;   // 1/sqrt(32)
        if (key < 49 && q < 49) {
          const int ky = key / 7, kx = key - ky*7;
          s += S.relb[wv][(ky - qy + 6)*13 + (kx - qx + 6)];
          if (hb == 7 && ((qy >= 4) != (ky >= 4))) s = NEGHUGE;  // UL mask
        } else {
          s = NEGHUGE;
        }
        sc[mt][n][r] = s;
      }
      float mx = fmaxf(fmaxf(sc[mt][0][r], sc[mt][1][r]),
                       fmaxf(sc[mt][2][r], sc[mt][3][r]));
      mx = fmaxf(mx, __shfl_xor(mx, 1));
      mx = fmaxf(mx, __shfl_xor(mx, 2));
      mx = fmaxf(mx, __shfl_xor(mx, 4));
      mx = fmaxf(mx, __shfl_xor(mx, 8));
      float sum = 0.f;
      #pragma unroll
      for (int n = 0; n < 4; ++n) {
        float p = exp2f((sc[mt][n][r] - mx) * 1.4426950408889634f);
        sc[mt][n][r] = p; sum += p;
      }
      sum += __shfl_xor(sum, 1);
      sum += __shfl_xor(sum, 2);
      sum += __shfl_xor(sum, 4);
      sum += __shfl_xor(sum, 8);
      const float rinv = 1.0f / sum;
      #pragma unroll
      for (int n = 0; n < 4; ++n)
        S.P[wv][q][n*16 + l16] = f2b(sc[mt][n][r] * rinv);
    }
  __syncthreads();

  // PV; store at rolled (+3) coordinates
  #pragma unroll
  for (int mt = 0; mt < 4; ++mt) {
    bf16x8 ap0 = *(const bf16x8*)(&S.P[wv][mt*16 + l16][quad*8]);
    bf16x8 ap1 = *(const bf16x8*)(&S.P[wv][mt*16 + l16][32 + quad*8]);
    #pragma unroll
    for (int n2 = 0; n2 < 2; ++n2) {
      bf16x8 bv0 = *(const bf16x8*)(&S.Vt[wv][n2*16 + l16][quad*8]);
      bf16x8 bv1 = *(const bf16x8*)(&S.Vt[wv][n2*16 + l16][32 + quad*8]);
      f32x4 o = {0.f,0.f,0.f,0.f};
      o = MFMA16(ap0, bv0, o);
      o = MFMA16(ap1, bv1, o);
      #pragma unroll
      for (int r = 0; r < 4; ++r) {
        int q = mt*16 + quad*4 + r;
        if (q < 49) {
          int py = q / 7, px = q - py*7;
          int hh = hb*7 + py + 3; if (hh >= 56) hh -= 56;  // inverse roll here
          int ww = wb*7 + px + 3; if (ww >= 56) ww -= 56;
          attnb[(size_t)((b*56 + hh)*56 + ww)*384
                + head*32 + n2*16 + l16] = f2b(o[r]);
        }
      }
    }
  }
}

// ---------------- kernel 4: out = attn @ w_out^T + b_out, fully linear -------
__global__ __launch_bounds__(384, 4) void k_proj(
    const u16* __restrict__ attnb, const u16* __restrict__ woutb,
    const float* __restrict__ bout, float* __restrict__ out)
{
  __shared__ u16 At[32][392];   // attn m-tile, staged once, read by 6 waves
  const int tid = threadIdx.x;
  const int wv = tid >> 6, lane = tid & 63, quad = lane >> 4, l16 = lane & 15;
  const int m0 = (int)blockIdx.x * 32;               // 1568 blocks
  const int n0 = wv * 64;                            // 6 waves cover N=384

  for (int i = tid; i < 32*48; i += 384) {
    int row = i / 48, g = i % 48;
    *(uint4*)(&At[row][g*8]) =
        *(const uint4*)(&attnb[(size_t)(m0 + row)*384 + g*8]);
  }
  __syncthreads();

  f32x4 acc[2][4];
  #pragma unroll
  for (int mi = 0; mi < 2; ++mi)
    #pragma unroll
    for (int j = 0; j < 4; ++j) acc[mi][j] = f32x4{0.f,0.f,0.f,0.f};

  for (int k = 0; k < 12; ++k) {
    bf16x8 a[2], bb[4];
    #pragma unroll
    for (int mi = 0; mi < 2; ++mi)
      a[mi] = *(const bf16x8*)(&At[mi*16 + l16][k*32 + quad*8]);
    #pragma unroll
    for (int j = 0; j < 4; ++j)
      bb[j] = *(const bf16x8*)(&woutb[(size_t)(n0 + j*16 + l16)*384 + k*32 + quad*8]);
    #pragma unroll
    for (int mi = 0; mi < 2; ++mi)
      #pragma unroll
      for (int j = 0; j < 4; ++j)
        acc[mi][j] = MFMA16(a[mi], bb[j], acc[mi][j]);
  }

  float bias[4];
  #pragma unroll
  for (int j = 0; j < 4; ++j) bias[j] = bout[n0 + j*16 + l16];

  // linear stores; j-inner so the 4x64B segments of each 256B span merge
  #pragma unroll
  for (int mi = 0; mi < 2; ++mi)
    #pragma unroll
    for (int r = 0; r < 4; ++r) {
      const int m = m0 + mi*16 + quad*4 + r;
      float* dst = out + (size_t)m*384 + n0;
      #pragma unroll
      for (int j = 0; j < 4; ++j)
        dst[j*16 + l16] = acc[mi][j][r] + bias[j];
    }
}

extern "C" void kernel_launch(void* const* d_in, const int* in_sizes, int n_in,
                              void* d_out, int out_size, void* d_ws, size_t ws_size,
                              hipStream_t stream) {
  const float* x    = (const float*)d_in[0];
  const float* wqkv = (const float*)d_in[1];
  const float* wout = (const float*)d_in[2];
  const float* bout = (const float*)d_in[3];
  const float* relt = (const float*)d_in[4];

  char* ws = (char*)d_ws;
  u16* qkvs  = (u16*)(ws);                        // 115,605,504 B
  u16* wqkvb = (u16*)(ws + 115605504);            //     884,736 B
  u16* woutb = (u16*)(ws + 116490240);            //     294,912 B
  u16* attnb = (u16*)(ws + 116785152);            //  38,535,168 B
  float* outp = (float*)d_out;

  k_convert_w<<<576, 256, 0, stream>>>(wqkv, wout, wqkvb, woutb);
  k_qkv<<<2352, 384, 0, stream>>>(x, wqkvb, qkvs);
  k_attn<<<3072, 256, 0, stream>>>(qkvs, relt, attnb);
  k_proj<<<1568, 384, 0, stream>>>(attnb, woutb, bout, outp);
}